// Round 10
// baseline (133.721 us; speedup 1.0000x reference)
//
#include <hip/hip_runtime.h>

#define N_ROWS 8192
#define NX     4096
#define DIM    512
#define NT     64           // 128-row tile units per side
#define NBLK   1056         // sum_ti (32 - (ti>>1)) : 128x256 upper-tri tiles
#define BK     32           // K elements per stage (64 B per row)

typedef __bf16 bf16_t;
typedef bf16_t bf16x8 __attribute__((ext_vector_type(8)));
typedef float  f32x4  __attribute__((ext_vector_type(4)));

#if __has_builtin(__builtin_amdgcn_exp2f)
  #define EXP2F __builtin_amdgcn_exp2f
#else
  #define EXP2F exp2f
#endif

// ws layout (bytes):
//   0       sqrow[8192]  float   (32768 B)   exact fp32 row norms
//   32768   colsum[512]  float   ( 2048 B)
//   34816   cvals[5]     float   (   20 B)   cvals[k] = -log2e/(bw*mult_k)
//   34840   tk1          uint    (    4 B)   colsum ticket
//   34844   tk2          uint    (    4 B)   pair ticket
//   34848   S1acc        double  (    8 B)   sum of sqrow
//   34944   acc[8*16]    double  ( 1024 B)   8 accumulation slots, 128 B apart
//   36864   Zh[8192*512] bf16    (8388608 B) bf16 copy of concat(X,Y)
//
// NO __threadfence anywhere (R7/R8 A/B: the per-block L2 writeback doubled
// k_pair's stage-load latency chip-wide; 108 -> 65 us when removed).
// Ordering: returning atomic -> asm sink -> s_waitcnt vmcnt(0) -> ticket.

__device__ __forceinline__ const float* zrow(const float* X, const float* Y, int r) {
    return (r < NX) ? (X + (size_t)r * DIM) : (Y + (size_t)(r - NX) * DIM);
}

// async 16B global -> LDS (lane-contiguous dest: ldsbase + lane*16)
__device__ __forceinline__ void gload_lds16(const bf16_t* g, bf16_t* l) {
    __builtin_amdgcn_global_load_lds(
        (__attribute__((address_space(1))) void*)(void*)(g),
        (__attribute__((address_space(3))) void*)(void*)(l), 16, 0, 0);
}

// fused: bf16 copy + exact fp32 row norms + zero-init of colsum/tickets.
__global__ void k_prep(const float* __restrict__ X, const float* __restrict__ Y,
                       bf16_t* __restrict__ Zh, float* __restrict__ sqrow,
                       float* __restrict__ colsum, unsigned* __restrict__ tk1,
                       double* __restrict__ S1acc) {
    int t = threadIdx.x;
    if (blockIdx.x == 0) {
        colsum[t] = 0.f; colsum[t + 256] = 0.f;
        if (t == 0) { *tk1 = 0u; *S1acc = 0.0; }
    }
    int wv = t >> 6, lane = t & 63;
    int row = blockIdx.x * 4 + wv;
    const float4* z4 = (const float4*)zrow(X, Y, row);
    float4 a = z4[lane * 2], b = z4[lane * 2 + 1];
    bf16x8 h;
    h[0] = (bf16_t)a.x; h[1] = (bf16_t)a.y; h[2] = (bf16_t)a.z; h[3] = (bf16_t)a.w;
    h[4] = (bf16_t)b.x; h[5] = (bf16_t)b.y; h[6] = (bf16_t)b.z; h[7] = (bf16_t)b.w;
    *(bf16x8*)(Zh + (size_t)row * DIM + lane * 8) = h;
    float s = a.x*a.x + a.y*a.y + a.z*a.z + a.w*a.w
            + b.x*b.x + b.y*b.y + b.z*b.z + b.w*b.w;
    #pragma unroll
    for (int off = 32; off > 0; off >>= 1) s += __shfl_down(s, off);
    if (lane == 0) sqrow[row] = s;
}

// colsum + S1 + bw, fused. 128 blocks = 16 col-groups x 8 row-slabs.
// Fence-free ticket ordering (returning atomics + vmcnt(0)).
__global__ __launch_bounds__(512) void k_colsum(const bf16_t* __restrict__ Zh,
                                                const float* __restrict__ sqrow,
                                                float* __restrict__ colsum,
                                                float* __restrict__ cvals,
                                                double* __restrict__ S1acc,
                                                unsigned* __restrict__ tk1,
                                                double* __restrict__ acc,
                                                unsigned* __restrict__ tk2) {
    __shared__ float red[8][4][8];
    __shared__ double dred[512];
    __shared__ int is_last;
    int t = threadIdx.x, lane = t & 63, wv = t >> 6;
    int n16 = lane & 15, q16 = lane >> 4;
    int g = blockIdx.x & 15, slab = blockIdx.x >> 4;
    int c0 = g * 32 + q16 * 8;
    float s[8] = {0.f, 0.f, 0.f, 0.f, 0.f, 0.f, 0.f, 0.f};
    #pragma unroll
    for (int it = 0; it < 8; ++it) {
        int r = slab * 1024 + it * 128 + wv * 16 + n16;
        bf16x8 v = *(const bf16x8*)(Zh + (size_t)r * DIM + c0);
        #pragma unroll
        for (int j = 0; j < 8; ++j) s[j] += (float)v[j];
    }
    #pragma unroll
    for (int off = 8; off >= 1; off >>= 1)
        #pragma unroll
        for (int j = 0; j < 8; ++j) s[j] += __shfl_down(s[j], off);
    if (n16 == 0)
        #pragma unroll
        for (int j = 0; j < 8; ++j) red[wv][q16][j] = s[j];
    __syncthreads();
    float oldc = 0.f;
    if (t < 32) {
        int q = t >> 3, j = t & 7;
        float v = 0.f;
        #pragma unroll
        for (int w = 0; w < 8; ++w) v += red[w][q][j];
        oldc = atomicAdd(&colsum[g * 32 + q * 8 + j], v);   // returning form
    }
    double olds = 0.0;
    if (g == 0) {   // S1 partial over this slab's 1024 rows (exact fp64)
        int i = slab * 1024 + t;
        double d = (double)sqrow[i] + (double)sqrow[i + 512];
        #pragma unroll
        for (int off = 32; off > 0; off >>= 1) d += __shfl_down(d, off);
        if (lane == 0) olds = atomicAdd(S1acc, d);          // returning form
    }
    asm volatile("" :: "v"(oldc), "v"(olds));               // keep returns live
    asm volatile("s_waitcnt vmcnt(0)" ::: "memory");        // atomics completed
    __syncthreads();
    if (t == 0) is_last = (atomicAdd(tk1, 1u) == 127u);
    __syncthreads();
    if (!is_last) return;
    // last block: bw = (2n*S1 - 2*CS) / (n^2 - n)
    float cv = atomicAdd(&colsum[t], 0.f);   // atomic read (coherent)
    dred[t] = (double)cv * (double)cv;
    __syncthreads();
    for (int off = 256; off > 0; off >>= 1) {
        if (t < off) dred[t] += dred[t + off];
        __syncthreads();
    }
    if (t < 8) acc[t * 16] = 0.0;
    if (t == 0) {
        double S1 = atomicAdd(S1acc, 0.0);   // atomic read
        double n = (double)N_ROWS;
        double sumD2 = 2.0 * n * S1 - 2.0 * dred[0];
        double bw = sumD2 / (n * n - n);
        const double LOG2E = 1.4426950408889634;
        double mult = 0.25;
        for (int k = 0; k < 5; ++k) {
            cvals[k] = (float)(-LOG2E / (bw * mult));
            mult *= 2.0;
        }
        *tk2 = 0u;
    }
}

// 128x256 tile (one A-panel shared by two 128-col halves): halves total
// barrier convoys (1056 blocks x 16 steps vs 2080 x 16) and cuts stage
// traffic 24%; 32 MFMA per wave per barrier. Depth-2 pipelined staging,
// 3 buffers (72 KB -> 2 blocks/CU), one raw s_barrier per K-step, counted
// s_waitcnt vmcnt(6) (6 gload_lds/thread/step; never 0 in main loop).
// Stage s+2 issues after barrier s into buf (s+2)%3 == (s-1)%3 whose
// readers provably finished. T5 setprio around the MFMA cluster.
// Layouts (m89/m91, verified absmax 0.0): A[m=lane&15][k=(lane>>4)*8+j];
// C/D col=lane&15, row=(lane>>4)*4+reg. XOR swizzle on GLOBAL side keeps
// frag ds_read_b128 conflict-free (gload_lds dest stays linear).
// Halves weighted independently: w_h = 0 if tj_h<ti else si*sj*(1|2).
// Fence-free ticketed final reduce at the tail.
__global__ __launch_bounds__(256, 2) void k_pair(const bf16_t* __restrict__ Zh,
                                                 const float* __restrict__ sqrow,
                                                 const float* __restrict__ cvals,
                                                 double* __restrict__ acc,
                                                 unsigned* __restrict__ tk2,
                                                 float* __restrict__ out) {
    // XCD-chunked swizzle (bijective: 1056 = 8 * 132), then decode L ->
    // (ti, tc): ti = 128-row tile 0..63, tc = 256-col tile >= ti>>1.
    // off(2M) = 64M - M(M-1); off(2M+1) = off(2M) + (32-M).
    int L0 = blockIdx.x;
    int L = (L0 & 7) * (NBLK / 8) + (L0 >> 3);
    int ti = 0;
    while (ti < NT - 1) {
        int nx = ti + 1, M = nx >> 1;
        int off = 64 * M - M * (M - 1) + ((nx & 1) ? (32 - M) : 0);
        if (off <= L) ti = nx; else break;
    }
    int Mi = ti >> 1;
    int offti = 64 * Mi - Mi * (Mi - 1) + ((ti & 1) ? (32 - Mi) : 0);
    int tc = (ti >> 1) + (L - offti);

    __shared__ bf16_t As[3][4096];   // A: 128 rows x 32 k  (8 KB/buf)
    __shared__ bf16_t Bs[3][8192];   // B: 256 rows x 32 k  (16 KB/buf)
    __shared__ float wsum[4][2];     // per-wave, per-half

    int t = threadIdx.x, lane = t & 63, wv = t >> 6;
    int wr = wv >> 1, wc = wv & 1;   // wave tile: 64 rows x 128 cols
    int i0 = ti * 128 + wr * 64;
    int j0 = tc * 256 + wc * 128;

    // staging: A instr h (2): chunk c=h*256+t; B instr h (4): same pattern.
    // chunk c: row r=c>>2, phys slot sq=c&3 holds logical q = sq^((r>>1)&3).
    const bf16_t* gA[2]; const bf16_t* gB[4];
    #pragma unroll
    for (int h = 0; h < 2; ++h) {
        int c = h * 256 + t, r = c >> 2, q = (c & 3) ^ ((r >> 1) & 3);
        gA[h] = Zh + (size_t)(ti * 128 + r) * DIM + q * 8;
    }
    #pragma unroll
    for (int h = 0; h < 4; ++h) {
        int c = h * 256 + t, r = c >> 2, q = (c & 3) ^ ((r >> 1) & 3);
        gB[h] = Zh + (size_t)(tc * 256 + r) * DIM + q * 8;
    }
    // wave-uniform LDS bases (lane*16B implicit)
    int ldsA0 = (wv * 64) * 8, ldsA1 = (256 + wv * 64) * 8;

    // fragment LDS element offsets (local row r, logical k-chunk q16)
    int n16 = lane & 15, q16 = lane >> 4;
    int aoff[4], boff[8];
    #pragma unroll
    for (int aa = 0; aa < 4; ++aa) {
        int r = wr * 64 + aa * 16 + n16;
        aoff[aa] = (r * 4 + (q16 ^ ((r >> 1) & 3))) * 8;
    }
    #pragma unroll
    for (int bb = 0; bb < 8; ++bb) {
        int r = wc * 128 + bb * 16 + n16;
        boff[bb] = (r * 4 + (q16 ^ ((r >> 1) & 3))) * 8;
    }

    f32x4 accf[4][8];
    #pragma unroll
    for (int a = 0; a < 4; ++a)
        #pragma unroll
        for (int b = 0; b < 8; ++b)
            accf[a][b] = (f32x4){0.f, 0.f, 0.f, 0.f};

#define STAGE(S) do {                                        \
        int _b = (S) % 3; int _kn = (S) * BK;                \
        gload_lds16(gA[0] + _kn, &As[_b][ldsA0]);            \
        gload_lds16(gA[1] + _kn, &As[_b][ldsA1]);            \
        gload_lds16(gB[0] + _kn, &Bs[_b][ldsA0]);            \
        gload_lds16(gB[1] + _kn, &Bs[_b][ldsA1]);            \
        gload_lds16(gB[2] + _kn, &Bs[_b][ldsA0 + 4096]);     \
        gload_lds16(gB[3] + _kn, &Bs[_b][ldsA1 + 4096]);     \
    } while (0)

#define KSTEP(S, VM, DO_STAGE) do {                                          \
        asm volatile("s_waitcnt vmcnt(" VM ")" ::: "memory");                \
        __builtin_amdgcn_s_barrier();                                        \
        __builtin_amdgcn_sched_barrier(0);                                   \
        if (DO_STAGE) STAGE((S) + 2);                                        \
        const bf16_t* Ab = &As[(S) % 3][0];                                  \
        const bf16_t* Bb = &Bs[(S) % 3][0];                                  \
        bf16x8 a[4], b[8];                                                   \
        _Pragma("unroll")                                                    \
        for (int aa = 0; aa < 4; ++aa) a[aa] = *(const bf16x8*)(Ab + aoff[aa]); \
        _Pragma("unroll")                                                    \
        for (int bb = 0; bb < 8; ++bb) b[bb] = *(const bf16x8*)(Bb + boff[bb]); \
        __builtin_amdgcn_s_setprio(1);                                       \
        _Pragma("unroll")                                                    \
        for (int aa = 0; aa < 4; ++aa)                                       \
            _Pragma("unroll")                                                \
            for (int bb = 0; bb < 8; ++bb)                                   \
                accf[aa][bb] = __builtin_amdgcn_mfma_f32_16x16x32_bf16(      \
                    a[aa], b[bb], accf[aa][bb], 0, 0, 0);                    \
        __builtin_amdgcn_s_setprio(0);                                       \
    } while (0)

    // prologue: stages 0,1 in flight (12 vmem/thread)
    STAGE(0); STAGE(1);
    // steady state: vmcnt(6) = stage s drained, s+1 (6 loads) outstanding
    KSTEP( 0, "6", 1); KSTEP( 1, "6", 1); KSTEP( 2, "6", 1); KSTEP( 3, "6", 1);
    KSTEP( 4, "6", 1); KSTEP( 5, "6", 1); KSTEP( 6, "6", 1); KSTEP( 7, "6", 1);
    KSTEP( 8, "6", 1); KSTEP( 9, "6", 1); KSTEP(10, "6", 1); KSTEP(11, "6", 1);
    KSTEP(12, "6", 1); KSTEP(13, "6", 1);    // stage 15 issued here
    KSTEP(14, "6", 0);                       // outstanding: 15 = 6
    KSTEP(15, "0", 0);                       // drain
#undef KSTEP
#undef STAGE

    // epilogue: D2 -> 5-bandwidth RBF via squaring chain, halves separate
    float c4 = cvals[4];
    float sqi[4][4], sqj[8];
    #pragma unroll
    for (int aa = 0; aa < 4; ++aa)
        #pragma unroll
        for (int r = 0; r < 4; ++r)
            sqi[aa][r] = sqrow[i0 + 16 * aa + q16 * 4 + r];
    #pragma unroll
    for (int bb = 0; bb < 8; ++bb)
        sqj[bb] = sqrow[j0 + 16 * bb + n16];

    float s0 = 0.f, s1 = 0.f;
    #pragma unroll
    for (int aa = 0; aa < 4; ++aa) {
        #pragma unroll
        for (int bb = 0; bb < 8; ++bb) {
            float part = 0.f;
            #pragma unroll
            for (int r = 0; r < 4; ++r) {
                float d2 = fmaf(-2.f, accf[aa][bb][r], sqi[aa][r] + sqj[bb]);
                d2 = fmaxf(d2, 0.f);
                float e4 = EXP2F(d2 * c4);       // smallest |c|
                float e3 = e4 * e4;
                float e2 = e3 * e3;
                float e1 = e2 * e2;
                float e0 = e1 * e1;
                part += e4 + e3 + e2 + e1 + e0;
            }
            // half = (wc*128 + bb*16) < 128 ? 0 : 1  -> wc==0: bb<8 all h
            if ((wc == 0 && bb < 8 && (bb * 16 < 128)) || (wc == 1 && false)) {}
            if (wc == 0) { if (bb < 8) { if (bb * 16 < 128) s0 += part; } }
            else s1 += part;
        }
    }
    // NOTE: wc==0 wave covers cols [0,128) -> all its bb are half 0;
    // wc==1 wave covers cols [128,256) -> all half 1. (branch above folds)
    #pragma unroll
    for (int off = 32; off > 0; off >>= 1) {
        s0 += __shfl_down(s0, off);
        s1 += __shfl_down(s1, off);
    }
    if (lane == 0) { wsum[wv][0] = s0; wsum[wv][1] = s1; }
    __syncthreads();
    if (t == 0) {
        // wc==0 waves (wv 0,2) contributed to slot 0; wc==1 (wv 1,3) slot 1
        float bs0 = wsum[0][0] + wsum[2][0];
        float bs1 = wsum[1][1] + wsum[3][1];
        int tj0 = 2 * tc, tj1 = 2 * tc + 1;
        double si = (ti < 32) ? 1.0 : -1.0;
        double w0 = (tj0 < ti) ? 0.0
                  : si * ((tj0 < 32) ? 1.0 : -1.0) * ((tj0 == ti) ? 1.0 : 2.0);
        double w1 = (tj1 < ti) ? 0.0
                  : si * ((tj1 < 32) ? 1.0 : -1.0) * ((tj1 == ti) ? 1.0 : 2.0);
        double v = w0 * (double)bs0 + w1 * (double)bs1;
        // fence-free ordered ticket: returning atomic -> vmcnt(0) -> ticket
        double oldv = atomicAdd(&acc[(L0 & 7) * 16], v);
        asm volatile("" :: "v"(oldv));
        asm volatile("s_waitcnt vmcnt(0)" ::: "memory");
        unsigned old = atomicAdd(tk2, 1u);
        if (old == NBLK - 1) {               // last block: final reduce -> out
            double ssum = 0.0;
            #pragma unroll
            for (int i = 0; i < 8; ++i) ssum += atomicAdd(&acc[i * 16], 0.0);
            out[0] = (float)(ssum / ((double)NX * (double)NX));
        }
    }
}

extern "C" void kernel_launch(void* const* d_in, const int* in_sizes, int n_in,
                              void* d_out, int out_size, void* d_ws, size_t ws_size,
                              hipStream_t stream) {
    const float* X = (const float*)d_in[0];
    const float* Y = (const float*)d_in[1];
    float* out = (float*)d_out;

    float*    sqrow  = (float*)d_ws;
    float*    colsum = sqrow + 8192;
    float*    cvals  = (float*)((char*)d_ws + 34816);
    unsigned* tk1    = (unsigned*)((char*)d_ws + 34840);
    unsigned* tk2    = (unsigned*)((char*)d_ws + 34844);
    double*   S1acc  = (double*)((char*)d_ws + 34848);
    double*   acc    = (double*)((char*)d_ws + 34944);
    bf16_t*   Zh     = (bf16_t*)((char*)d_ws + 36864);

    k_prep  <<<2048, 256, 0, stream>>>(X, Y, Zh, sqrow, colsum, tk1, S1acc);
    k_colsum<<<128, 512, 0, stream>>>(Zh, sqrow, colsum, cvals, S1acc, tk1, acc, tk2);
    k_pair  <<<NBLK, 256, 0, stream>>>(Zh, sqrow, cvals, acc, tk2, out);
}

// Round 11
// 130.456 us; speedup vs baseline: 1.0250x; 1.0250x over previous
//
#include <hip/hip_runtime.h>

#define N_ROWS 8192
#define NX     4096
#define DIM    512
#define BT     128          // block tile (rows & cols)
#define NT     64           // N_ROWS / BT tiles per side
#define NTRI   2080         // NT*(NT+1)/2 upper-triangle tiles
#define BK     32           // K elements per stage (64 B per row)

typedef __bf16 bf16_t;
typedef bf16_t bf16x8 __attribute__((ext_vector_type(8)));
typedef float  f32x4  __attribute__((ext_vector_type(4)));

#if __has_builtin(__builtin_amdgcn_exp2f)
  #define EXP2F __builtin_amdgcn_exp2f
#else
  #define EXP2F exp2f
#endif

// ws layout (bytes):
//   0       sqrow[8192]  float   (32768 B)   exact fp32 row norms
//   32768   colsum[512]  float   ( 2048 B)
//   34816   cvals[5]     float   (   20 B)   cvals[k] = -log2e/(bw*mult_k)
//   34840   tk1          uint    (    4 B)   colsum ticket
//   34844   tk2          uint    (    4 B)   pair ticket
//   34848   S1acc        double  (    8 B)   sum of sqrow
//   34944   acc[8*16]    double  ( 1024 B)   8 accumulation slots, 128 B apart
//   36864   Zh[8192*512] bf16    (8388608 B) bf16 copy of concat(X,Y)
//
// NO __threadfence anywhere (R7/R8 A/B: per-block L2 writeback doubled
// k_pair's stage-load latency chip-wide; 108 -> 65 us when removed).
// Ordering: returning atomic -> asm sink -> s_waitcnt vmcnt(0) -> ticket.

__device__ __forceinline__ const float* zrow(const float* X, const float* Y, int r) {
    return (r < NX) ? (X + (size_t)r * DIM) : (Y + (size_t)(r - NX) * DIM);
}

// async 16B global -> LDS (lane-contiguous dest: ldsbase + lane*16)
__device__ __forceinline__ void gload_lds16(const bf16_t* g, bf16_t* l) {
    __builtin_amdgcn_global_load_lds(
        (__attribute__((address_space(1))) void*)(void*)(g),
        (__attribute__((address_space(3))) void*)(void*)(l), 16, 0, 0);
}

// fused: bf16 copy + exact fp32 row norms + zero-init of colsum/tickets.
__global__ void k_prep(const float* __restrict__ X, const float* __restrict__ Y,
                       bf16_t* __restrict__ Zh, float* __restrict__ sqrow,
                       float* __restrict__ colsum, unsigned* __restrict__ tk1,
                       double* __restrict__ S1acc) {
    int t = threadIdx.x;
    if (blockIdx.x == 0) {
        colsum[t] = 0.f; colsum[t + 256] = 0.f;
        if (t == 0) { *tk1 = 0u; *S1acc = 0.0; }
    }
    int wv = t >> 6, lane = t & 63;
    int row = blockIdx.x * 4 + wv;
    const float4* z4 = (const float4*)zrow(X, Y, row);
    float4 a = z4[lane * 2], b = z4[lane * 2 + 1];
    bf16x8 h;
    h[0] = (bf16_t)a.x; h[1] = (bf16_t)a.y; h[2] = (bf16_t)a.z; h[3] = (bf16_t)a.w;
    h[4] = (bf16_t)b.x; h[5] = (bf16_t)b.y; h[6] = (bf16_t)b.z; h[7] = (bf16_t)b.w;
    *(bf16x8*)(Zh + (size_t)row * DIM + lane * 8) = h;
    float s = a.x*a.x + a.y*a.y + a.z*a.z + a.w*a.w
            + b.x*b.x + b.y*b.y + b.z*b.z + b.w*b.w;
    #pragma unroll
    for (int off = 32; off > 0; off >>= 1) s += __shfl_down(s, off);
    if (lane == 0) sqrow[row] = s;
}

// colsum + S1 + bw, fused. 128 blocks = 16 col-groups x 8 row-slabs.
// Fence-free ticket ordering (returning atomics + vmcnt(0)).
__global__ __launch_bounds__(512) void k_colsum(const bf16_t* __restrict__ Zh,
                                                const float* __restrict__ sqrow,
                                                float* __restrict__ colsum,
                                                float* __restrict__ cvals,
                                                double* __restrict__ S1acc,
                                                unsigned* __restrict__ tk1,
                                                double* __restrict__ acc,
                                                unsigned* __restrict__ tk2) {
    __shared__ float red[8][4][8];
    __shared__ double dred[512];
    __shared__ int is_last;
    int t = threadIdx.x, lane = t & 63, wv = t >> 6;
    int n16 = lane & 15, q16 = lane >> 4;
    int g = blockIdx.x & 15, slab = blockIdx.x >> 4;
    int c0 = g * 32 + q16 * 8;
    float s[8] = {0.f, 0.f, 0.f, 0.f, 0.f, 0.f, 0.f, 0.f};
    #pragma unroll
    for (int it = 0; it < 8; ++it) {
        int r = slab * 1024 + it * 128 + wv * 16 + n16;
        bf16x8 v = *(const bf16x8*)(Zh + (size_t)r * DIM + c0);
        #pragma unroll
        for (int j = 0; j < 8; ++j) s[j] += (float)v[j];
    }
    #pragma unroll
    for (int off = 8; off >= 1; off >>= 1)
        #pragma unroll
        for (int j = 0; j < 8; ++j) s[j] += __shfl_down(s[j], off);
    if (n16 == 0)
        #pragma unroll
        for (int j = 0; j < 8; ++j) red[wv][q16][j] = s[j];
    __syncthreads();
    float oldc = 0.f;
    if (t < 32) {
        int q = t >> 3, j = t & 7;
        float v = 0.f;
        #pragma unroll
        for (int w = 0; w < 8; ++w) v += red[w][q][j];
        oldc = atomicAdd(&colsum[g * 32 + q * 8 + j], v);   // returning form
    }
    double olds = 0.0;
    if (g == 0) {   // S1 partial over this slab's 1024 rows (exact fp64)
        int i = slab * 1024 + t;
        double d = (double)sqrow[i] + (double)sqrow[i + 512];
        #pragma unroll
        for (int off = 32; off > 0; off >>= 1) d += __shfl_down(d, off);
        if (lane == 0) olds = atomicAdd(S1acc, d);          // returning form
    }
    asm volatile("" :: "v"(oldc), "v"(olds));               // keep returns live
    asm volatile("s_waitcnt vmcnt(0)" ::: "memory");        // atomics completed
    __syncthreads();
    if (t == 0) is_last = (atomicAdd(tk1, 1u) == 127u);
    __syncthreads();
    if (!is_last) return;
    // last block: bw = (2n*S1 - 2*CS) / (n^2 - n)
    float cv = atomicAdd(&colsum[t], 0.f);   // atomic read (coherent)
    dred[t] = (double)cv * (double)cv;
    __syncthreads();
    for (int off = 256; off > 0; off >>= 1) {
        if (t < off) dred[t] += dred[t + off];
        __syncthreads();
    }
    if (t < 8) acc[t * 16] = 0.0;
    if (t == 0) {
        double S1 = atomicAdd(S1acc, 0.0);   // atomic read
        double n = (double)N_ROWS;
        double sumD2 = 2.0 * n * S1 - 2.0 * dred[0];
        double bw = sumD2 / (n * n - n);
        const double LOG2E = 1.4426950408889634;
        double mult = 0.25;
        for (int k = 0; k < 5; ++k) {
            cvals[k] = (float)(-LOG2E / (bw * mult));
            mult *= 2.0;
        }
        *tk2 = 0u;
    }
}

// 128x128 tile over upper triangle; R3/R8 proven loop (3 stage buffers,
// 48 KB -> 3 blocks/CU, one raw s_barrier per K-step, counted vmcnt(4),
// T5 setprio). NEW this round:
//  (1) SUPERTILE-BLOCKED enumeration: tiles grouped into 8x8-tile
//      supertiles (8 diag x 36 + 28 off-diag x 64 = 2080). After XCD
//      chunking, one XCD's ~96 co-resident blocks span ~1.5 supertiles
//      -> ~8 A-panels + ~12 B-panels ~= 2.6 MB < 4 MB XCD L2, so stage
//      loads are L2 hits (~200 cy) instead of L3 (~600+ cy tail). R9
//      proved bytes aren't the binder; this targets SERVICE LATENCY.
//  (2) epilogue sqrow/cvals prefetched before STAGE(0): vmcnt(4) still
//      retires stage 0 exactly (prefetch loads are older, hence drained
//      by the same wait); kills the end-of-block serial load chain.
// Layouts (m89/m91, verified absmax 0.0): A[m=lane&15][k=(lane>>4)*8+j];
// C/D col=lane&15, row=(lane>>4)*4+reg. XOR swizzle on GLOBAL side keeps
// frag ds_read_b128 conflict-free (gload_lds dest stays linear).
// Fence-free ticketed final reduce at the tail.
__global__ __launch_bounds__(256, 3) void k_pair(const bf16_t* __restrict__ Zh,
                                                 const float* __restrict__ sqrow,
                                                 const float* __restrict__ cvals,
                                                 double* __restrict__ acc,
                                                 unsigned* __restrict__ tk2,
                                                 float* __restrict__ out) {
    // XCD-chunked swizzle (bijective: 2080 = 8 * 260)
    int L0 = blockIdx.x;
    int q = (L0 & 7) * (NTRI / 8) + (L0 >> 3);
    // supertile decode: row I of supertiles has 36 + (7-I)*64 tiles
    int ti, tj;
    {
        int I = 0, rem = q;
        #pragma unroll
        for (int it = 0; it < 8; ++it) {
            int rowcnt = 36 + (7 - I) * 64;
            if (rem >= rowcnt && I < 7) { rem -= rowcnt; ++I; } else break;
        }
        if (rem < 36) {            // diagonal supertile (I,I): pairs a<=b
            int a = 0;
            #pragma unroll
            for (int it = 0; it < 7; ++it) {
                int nxt = (a + 1) * 8 - (a + 1) * a / 2;   // offset(a+1)
                if (nxt <= rem) ++a; else break;
            }
            int off = a * 8 - a * (a - 1) / 2;
            ti = I * 8 + a;
            tj = I * 8 + a + (rem - off);
        } else {                   // off-diagonal supertile (I,J), J>I
            int r2 = rem - 36;
            int J = I + 1 + (r2 >> 6);
            int w = r2 & 63;
            ti = I * 8 + (w >> 3);
            tj = J * 8 + (w & 7);
        }
    }

    __shared__ bf16_t As[3][4096];   // 3 x 8 KB stage buffers
    __shared__ bf16_t Bs[3][4096];   // total 48 KB -> 3 blocks/CU
    __shared__ float wsum[4];

    int t = threadIdx.x, lane = t & 63, wv = t >> 6;
    int wr = wv >> 1, wc = wv & 1;
    int i0 = ti * BT + wr * 64;
    int j0 = tj * BT + wc * 64;

    // staging addressing: issue h covers chunks h*256+t; chunk c: row r=c>>2,
    // phys slot sq=c&3 holds logical chunk q = sq ^ ((r>>1)&3)
    const bf16_t* gA[2]; const bf16_t* gB[2];
    {
        int c0 = t, r0 = c0 >> 2, sq0 = c0 & 3, q0 = sq0 ^ ((r0 >> 1) & 3);
        int c1 = 256 + t, r1 = c1 >> 2, sq1 = c1 & 3, q1 = sq1 ^ ((r1 >> 1) & 3);
        gA[0] = Zh + (size_t)(ti * BT + r0) * DIM + q0 * 8;
        gB[0] = Zh + (size_t)(tj * BT + r0) * DIM + q0 * 8;
        gA[1] = Zh + (size_t)(ti * BT + r1) * DIM + q1 * 8;
        gB[1] = Zh + (size_t)(tj * BT + r1) * DIM + q1 * 8;
    }
    int ldsoff0 = (wv * 64) * 8;            // wave-uniform; lane*16B implicit
    int ldsoff1 = (256 + wv * 64) * 8;

    // fragment LDS element offsets (row r, logical k-chunk q16 -> phys slot)
    int n16 = lane & 15, q16 = lane >> 4;
    int aoff[4], boff[4];
    #pragma unroll
    for (int aa = 0; aa < 4; ++aa) {
        int r = 16 * (wr * 4 + aa) + n16;
        aoff[aa] = (r * 4 + (q16 ^ ((r >> 1) & 3))) * 8;
    }
    #pragma unroll
    for (int bb = 0; bb < 4; ++bb) {
        int r = 16 * (wc * 4 + bb) + n16;
        boff[bb] = (r * 4 + (q16 ^ ((r >> 1) & 3))) * 8;
    }

    // epilogue-data prefetch: issued BEFORE stage 0, so the loop's first
    // vmcnt(4) (stage0 done, stage1 in flight) also retires these.
    float c4 = cvals[4];
    float sqi[4][4], sqj[4];
    #pragma unroll
    for (int aa = 0; aa < 4; ++aa)
        #pragma unroll
        for (int r = 0; r < 4; ++r)
            sqi[aa][r] = sqrow[i0 + 16 * aa + q16 * 4 + r];
    #pragma unroll
    for (int bb = 0; bb < 4; ++bb)
        sqj[bb] = sqrow[j0 + 16 * bb + n16];

    f32x4 accf[4][4];
    #pragma unroll
    for (int a = 0; a < 4; ++a)
        #pragma unroll
        for (int b = 0; b < 4; ++b)
            accf[a][b] = (f32x4){0.f, 0.f, 0.f, 0.f};

#define STAGE(S) do {                                   \
        int _b = (S) % 3; int _kn = (S) * BK;           \
        gload_lds16(gA[0] + _kn, &As[_b][ldsoff0]);     \
        gload_lds16(gB[0] + _kn, &Bs[_b][ldsoff0]);     \
        gload_lds16(gA[1] + _kn, &As[_b][ldsoff1]);     \
        gload_lds16(gB[1] + _kn, &Bs[_b][ldsoff1]);     \
    } while (0)

#define KSTEP(S, VM, DO_STAGE) do {                                          \
        asm volatile("s_waitcnt vmcnt(" VM ")" ::: "memory");                \
        __builtin_amdgcn_s_barrier();                                        \
        __builtin_amdgcn_sched_barrier(0);                                   \
        if (DO_STAGE) STAGE((S) + 2);                                        \
        const bf16_t* Ab = &As[(S) % 3][0];                                  \
        const bf16_t* Bb = &Bs[(S) % 3][0];                                  \
        bf16x8 a[4], b[4];                                                   \
        _Pragma("unroll")                                                    \
        for (int aa = 0; aa < 4; ++aa) a[aa] = *(const bf16x8*)(Ab + aoff[aa]); \
        _Pragma("unroll")                                                    \
        for (int bb = 0; bb < 4; ++bb) b[bb] = *(const bf16x8*)(Bb + boff[bb]); \
        __builtin_amdgcn_s_setprio(1);                                       \
        _Pragma("unroll")                                                    \
        for (int aa = 0; aa < 4; ++aa)                                       \
            _Pragma("unroll")                                                \
            for (int bb = 0; bb < 4; ++bb)                                   \
                accf[aa][bb] = __builtin_amdgcn_mfma_f32_16x16x32_bf16(      \
                    a[aa], b[bb], accf[aa][bb], 0, 0, 0);                    \
        __builtin_amdgcn_s_setprio(0);                                       \
    } while (0)

    // prologue: stages 0,1 in flight (8 vmem/thread, after prefetch loads)
    STAGE(0); STAGE(1);
    // steady state: wait vmcnt(4) = stage s drained, s+1 outstanding
    KSTEP( 0, "4", 1); KSTEP( 1, "4", 1); KSTEP( 2, "4", 1); KSTEP( 3, "4", 1);
    KSTEP( 4, "4", 1); KSTEP( 5, "4", 1); KSTEP( 6, "4", 1); KSTEP( 7, "4", 1);
    KSTEP( 8, "4", 1); KSTEP( 9, "4", 1); KSTEP(10, "4", 1); KSTEP(11, "4", 1);
    KSTEP(12, "4", 1); KSTEP(13, "4", 1);    // stage 15 issued here
    KSTEP(14, "4", 0);                       // outstanding: 15 = 4
    KSTEP(15, "0", 0);                       // drain
#undef KSTEP
#undef STAGE

    // epilogue: D2 -> 5-bandwidth RBF via squaring chain:
    // c_k halves per k => e_k = e4^(2^(4-k)); 1 exp + 4 muls per d2
    float s_local = 0.f;
    #pragma unroll
    for (int aa = 0; aa < 4; ++aa) {
        #pragma unroll
        for (int bb = 0; bb < 4; ++bb) {
            #pragma unroll
            for (int r = 0; r < 4; ++r) {
                float d2 = fmaf(-2.f, accf[aa][bb][r], sqi[aa][r] + sqj[bb]);
                d2 = fmaxf(d2, 0.f);
                float e4 = EXP2F(d2 * c4);       // smallest |c|
                float e3 = e4 * e4;
                float e2 = e3 * e3;
                float e1 = e2 * e2;
                float e0 = e1 * e1;
                s_local += e4 + e3 + e2 + e1 + e0;
            }
        }
    }
    #pragma unroll
    for (int off = 32; off > 0; off >>= 1) s_local += __shfl_down(s_local, off);
    if (lane == 0) wsum[wv] = s_local;
    __syncthreads();
    if (t == 0) {
        float bs = wsum[0] + wsum[1] + wsum[2] + wsum[3];
        double si = (ti < NT / 2) ? 1.0 : -1.0;
        double sj = (tj < NT / 2) ? 1.0 : -1.0;
        double w = si * sj * ((ti == tj) ? 1.0 : 2.0);
        // fence-free ordered ticket: returning atomic -> vmcnt(0) -> ticket
        double oldv = atomicAdd(&acc[(L0 & 7) * 16], w * (double)bs);
        asm volatile("" :: "v"(oldv));
        asm volatile("s_waitcnt vmcnt(0)" ::: "memory");
        unsigned old = atomicAdd(tk2, 1u);
        if (old == NTRI - 1) {               // last block: final reduce -> out
            double ssum = 0.0;
            #pragma unroll
            for (int i = 0; i < 8; ++i) ssum += atomicAdd(&acc[i * 16], 0.0);
            out[0] = (float)(ssum / ((double)NX * (double)NX));
        }
    }
}

extern "C" void kernel_launch(void* const* d_in, const int* in_sizes, int n_in,
                              void* d_out, int out_size, void* d_ws, size_t ws_size,
                              hipStream_t stream) {
    const float* X = (const float*)d_in[0];
    const float* Y = (const float*)d_in[1];
    float* out = (float*)d_out;

    float*    sqrow  = (float*)d_ws;
    float*    colsum = sqrow + 8192;
    float*    cvals  = (float*)((char*)d_ws + 34816);
    unsigned* tk1    = (unsigned*)((char*)d_ws + 34840);
    unsigned* tk2    = (unsigned*)((char*)d_ws + 34844);
    double*   S1acc  = (double*)((char*)d_ws + 34848);
    double*   acc    = (double*)((char*)d_ws + 34944);
    bf16_t*   Zh     = (bf16_t*)((char*)d_ws + 36864);

    k_prep  <<<2048, 256, 0, stream>>>(X, Y, Zh, sqrow, colsum, tk1, S1acc);
    k_colsum<<<128, 512, 0, stream>>>(Zh, sqrow, colsum, cvals, S1acc, tk1, acc, tk2);
    k_pair  <<<NTRI, 256, 0, stream>>>(Zh, sqrow, cvals, acc, tk2, out);
}